// Round 3
// baseline (11277.129 us; speedup 1.0000x reference)
//
#include <hip/hip_runtime.h>
#include <cstddef>

// ---- bf16 helpers (round-to-nearest-even) ---------------------------------
__device__ __forceinline__ unsigned short f2bf(float f) {
    unsigned u = __float_as_uint(f);
    u += 0x7FFFu + ((u >> 16) & 1u);
    return (unsigned short)(u >> 16);
}
__device__ __forceinline__ float bf2f(unsigned short h) {
    return __uint_as_float((unsigned)h << 16);
}
__device__ __forceinline__ float ldv(const float* p) { return *p; }
__device__ __forceinline__ float ldv(const unsigned short* p) { return bf2f(*p); }

// ---------------------------------------------------------------------------
// Fused conv1(3->64,s1) + relu + conv2(64->128,s2) + relu.
// Grid: (4x32 tiles, 2 co-blocks, 16 n). Block 256 = 16 co-grp x 16 x-grp.
// conv2 out tile: 64co x 4y x 32x. h1 chunk (8 ch) computed in LDS from x patch.
// ---------------------------------------------------------------------------
__global__ __launch_bounds__(256)
void fused_conv12_kernel(const float* __restrict__ x,   // [16,3,256,256]
                         const float* __restrict__ w1,  // [64,3,3,3]
                         const float* __restrict__ b1,
                         const float* __restrict__ w2,  // [128,64,3,3]
                         const float* __restrict__ b2,
                         float* __restrict__ out)       // [16,128,128,128]
{
    __shared__ float s_x[3][11][67];
    __shared__ float s_w1[64][28];
    __shared__ float s_h1[8][9][65];
    __shared__ float s_w2[72][65];

    const int tid = threadIdx.x;
    const int tx = tid & 15, ty = tid >> 4;
    const int tileX = blockIdx.x & 3;
    const int tileY = blockIdx.x >> 2;
    const int x0 = tileX * 32, y0 = tileY * 4;
    const int co0 = blockIdx.y * 64;
    const int n = blockIdx.z;
    const float* xN = x + (size_t)n * 3 * 65536;

    const int gy0 = 2 * y0 - 2, gx0 = 2 * x0 - 2;   // x patch origin
    const int hy0 = 2 * y0 - 1, hx0 = 2 * x0 - 1;   // h1 tile origin

    for (int e = tid; e < 3 * 11 * 67; e += 256) {
        int c = e / 737, r = e % 737;
        int yy = r / 67, xx = r % 67;
        int gy = gy0 + yy, gx = gx0 + xx;
        float v = 0.f;
        if ((unsigned)gy < 256u && (unsigned)gx < 256u)
            v = xN[(size_t)c * 65536 + gy * 256 + gx];
        s_x[c][yy][xx] = v;
    }
    for (int e = tid; e < 64 * 27; e += 256)
        s_w1[e / 27][e % 27] = w1[e];

    float acc[4][4][2] = {};

    for (int ci0 = 0; ci0 < 64; ci0 += 8) {
        __syncthreads();   // covers initial staging AND prev-iter readers
        // compute h1 chunk (conv1 + relu; zero = conv2's padding)
        for (int e = tid; e < 8 * 9 * 65; e += 256) {
            int m = e / 585, r = e % 585;
            int ly = r / 65, lx = r % 65;
            float v = 0.f;
            if ((unsigned)(hy0 + ly) < 256u && (unsigned)(hx0 + lx) < 256u) {
                const int gm = ci0 + m;
                float s = b1[gm];
#pragma unroll
                for (int c = 0; c < 3; c++)
#pragma unroll
                    for (int ky = 0; ky < 3; ky++)
#pragma unroll
                        for (int kx = 0; kx < 3; kx++)
                            s += s_w1[gm][c * 9 + ky * 3 + kx] * s_x[c][ly + ky][lx + kx];
                v = fmaxf(s, 0.f);
            }
            s_h1[m][ly][lx] = v;
        }
        // stage w2 chunk
        for (int e = tid; e < 64 * 72; e += 256) {
            int co = e / 72, r = e % 72;
            s_w2[r][co] = w2[(size_t)(co0 + co) * 576 + ci0 * 9 + r];
        }
        __syncthreads();
        // conv2 accumulate (stride 2)
#pragma unroll
        for (int ci = 0; ci < 8; ++ci) {
#pragma unroll
            for (int k = 0; k < 9; ++k) {
                const int ky = k / 3, kx = k % 3;
                float wv[4];
#pragma unroll
                for (int i = 0; i < 4; i++) wv[i] = s_w2[ci * 9 + k][ty * 4 + i];
                float iv[4][2];
#pragma unroll
                for (int j = 0; j < 4; j++) {
                    iv[j][0] = s_h1[ci][j * 2 + ky][(tx * 2 + 0) * 2 + kx];
                    iv[j][1] = s_h1[ci][j * 2 + ky][(tx * 2 + 1) * 2 + kx];
                }
#pragma unroll
                for (int i = 0; i < 4; i++)
#pragma unroll
                    for (int j = 0; j < 4; j++) {
                        acc[i][j][0] += wv[i] * iv[j][0];
                        acc[i][j][1] += wv[i] * iv[j][1];
                    }
            }
        }
    }
#pragma unroll
    for (int i = 0; i < 4; i++) {
        const int co = co0 + ty * 4 + i;
        const float b = b2[co];
#pragma unroll
        for (int j = 0; j < 4; j++) {
            float2 v;
            v.x = fmaxf(acc[i][j][0] + b, 0.f);
            v.y = fmaxf(acc[i][j][1] + b, 0.f);
            *(float2*)(out + (size_t)((n * 128 + co) * 128 + (y0 + j)) * 128 + x0 + tx * 2) = v;
        }
    }
}

// ---------------------------------------------------------------------------
// Generic 3x3 conv, pad=1, stride 2, fp32 (encoder conv3/conv4).
// Block tile: 64 cout x (4y x 32x), thread = 4co x 4y x 2x.
// ---------------------------------------------------------------------------
template<int TIC, bool RELU>
__global__ __launch_bounds__(256)
void conv3x3s2_kernel(const float* __restrict__ in, const float* __restrict__ w,
                      const float* __restrict__ bias, float* __restrict__ out,
                      int CIN, int COUT, int IH, int IW, int OH, int OW)
{
    constexpr int IYT = 9, IXT = 65;
    __shared__ float s_in[TIC][IYT][IXT];
    __shared__ float s_w[TIC * 9][65];

    const int tid = threadIdx.x;
    const int tx = tid & 15;
    const int ty = tid >> 4;

    const int ntx = OW / 32;
    const int tileX = blockIdx.x % ntx;
    const int tileY = blockIdx.x / ntx;
    const int x0 = tileX * 32;
    const int y0 = tileY * 4;
    const int co0 = blockIdx.y * 64;
    const int n = blockIdx.z;

    const float* inN = in + (size_t)n * CIN * IH * IW;

    float acc[4][4][2] = {};

    const int iy0 = y0 * 2 - 1;
    const int ix0 = x0 * 2 - 1;

    for (int c0 = 0; c0 < CIN; c0 += TIC) {
        for (int e = tid; e < TIC * IYT * IXT; e += 256) {
            int ci = e / (IYT * IXT);
            int r  = e % (IYT * IXT);
            int yy = r / IXT, xx = r % IXT;
            int gy = iy0 + yy, gx = ix0 + xx;
            float v = 0.f;
            if ((unsigned)gy < (unsigned)IH && (unsigned)gx < (unsigned)IW)
                v = inN[(size_t)(c0 + ci) * IH * IW + (size_t)gy * IW + gx];
            s_in[ci][yy][xx] = v;
        }
        for (int e = tid; e < 64 * TIC * 9; e += 256) {
            int co = e / (TIC * 9);
            int r  = e % (TIC * 9);
            s_w[r][co] = w[(size_t)(co0 + co) * CIN * 9 + (size_t)c0 * 9 + r];
        }
        __syncthreads();
#pragma unroll
        for (int ci = 0; ci < TIC; ++ci) {
#pragma unroll
            for (int k = 0; k < 9; ++k) {
                const int ky = k / 3, kx = k % 3;
                float wv[4];
#pragma unroll
                for (int i = 0; i < 4; i++) wv[i] = s_w[ci * 9 + k][ty * 4 + i];
                float iv[4][2];
#pragma unroll
                for (int j = 0; j < 4; j++) {
                    iv[j][0] = s_in[ci][j * 2 + ky][(tx * 2 + 0) * 2 + kx];
                    iv[j][1] = s_in[ci][j * 2 + ky][(tx * 2 + 1) * 2 + kx];
                }
#pragma unroll
                for (int i = 0; i < 4; i++)
#pragma unroll
                    for (int j = 0; j < 4; j++) {
                        acc[i][j][0] += wv[i] * iv[j][0];
                        acc[i][j][1] += wv[i] * iv[j][1];
                    }
            }
        }
        __syncthreads();
    }

#pragma unroll
    for (int i = 0; i < 4; i++) {
        const int co = co0 + ty * 4 + i;
        const float b = bias[co];
#pragma unroll
        for (int j = 0; j < 4; j++) {
            float2 v;
            v.x = acc[i][j][0] + b;
            v.y = acc[i][j][1] + b;
            if (RELU) { v.x = fmaxf(v.x, 0.f); v.y = fmaxf(v.y, 0.f); }
            *(float2*)(out + (size_t)((n * COUT + co) * OH + (y0 + j)) * OW + x0 + tx * 2) = v;
        }
    }
}

// ---------------------------------------------------------------------------
__global__ __launch_bounds__(64)
void cnorm_kernel(const float* __restrict__ cb, float* __restrict__ cn)
{
    const int code = blockIdx.x;
    const int t = threadIdx.x;
    const float* row = cb + (size_t)code * 512;
    float s = 0.f;
    for (int i = t; i < 512; i += 64) s += row[i] * row[i];
#pragma unroll
    for (int off = 32; off > 0; off >>= 1) s += __shfl_down(s, off, 64);
    if (t == 0) cn[code] = s;
}

__global__ __launch_bounds__(256)
void init_keys_kernel(unsigned long long* __restrict__ keys)
{
    keys[blockIdx.x * 256 + threadIdx.x] = ~0ull;
}

// ---------------------------------------------------------------------------
// VQ distance GEMM + argmin.  score = |c|^2 - 2 z.c
// ---------------------------------------------------------------------------
__global__ __launch_bounds__(256)
void vq_dist_kernel(const float* __restrict__ z,   // [16,512,32,32]
                    const float* __restrict__ cb,  // [8192,512]
                    const float* __restrict__ cn,
                    unsigned long long* __restrict__ keys) // [16384]
{
    __shared__ float sA[16][132];
    __shared__ float sB[16][132];
    __shared__ unsigned long long sred[128][17];

    const int t = threadIdx.x;
    const int tr = t & 15, tc = t >> 4;
    const int v0 = blockIdx.x * 128;
    const int code0 = blockIdx.y * 128;
    const int n = v0 >> 10;
    const int hw0 = v0 & 1023;
    const float* zN = z + (size_t)n * 512 * 1024;

    float acc[8][8] = {};

    for (int k0 = 0; k0 < 512; k0 += 16) {
        for (int e = t; e < 512; e += 256) {
            int kk = e >> 5;
            int r4 = e & 31;
            const float4 v = *(const float4*)(zN + (size_t)(k0 + kk) * 1024 + hw0 + r4 * 4);
            *(float4*)&sA[kk][r4 * 4] = v;
        }
        for (int e = t; e < 512; e += 256) {
            int code = e >> 2;
            int q = e & 3;
            const float4 v = *(const float4*)(cb + (size_t)(code0 + code) * 512 + k0 + q * 4);
            sB[q * 4 + 0][code] = v.x;
            sB[q * 4 + 1][code] = v.y;
            sB[q * 4 + 2][code] = v.z;
            sB[q * 4 + 3][code] = v.w;
        }
        __syncthreads();
#pragma unroll
        for (int k = 0; k < 16; ++k) {
            float a[8], b[8];
            *(float4*)&a[0] = *(const float4*)&sA[k][tr * 8];
            *(float4*)&a[4] = *(const float4*)&sA[k][tr * 8 + 4];
            *(float4*)&b[0] = *(const float4*)&sB[k][tc * 8];
            *(float4*)&b[4] = *(const float4*)&sB[k][tc * 8 + 4];
#pragma unroll
            for (int i = 0; i < 8; i++)
#pragma unroll
                for (int j = 0; j < 8; j++)
                    acc[i][j] += a[i] * b[j];
        }
        __syncthreads();
    }

#pragma unroll
    for (int i = 0; i < 8; i++) {
        float best = 3.0e38f;
        int bj = 0;
#pragma unroll
        for (int j = 0; j < 8; j++) {
            float s = cn[code0 + tc * 8 + j] - 2.0f * acc[i][j];
            if (s < best) { best = s; bj = j; }
        }
        unsigned u = __float_as_uint(best);
        u = (u & 0x80000000u) ? ~u : (u | 0x80000000u);
        unsigned long long key = ((unsigned long long)u << 32) |
                                 (unsigned)(code0 + tc * 8 + bj);
        sred[tr * 8 + i][tc] = key;
    }
    __syncthreads();
    if (t < 128) {
        unsigned long long m = sred[t][0];
#pragma unroll
        for (int c = 1; c < 16; c++) {
            unsigned long long v = sred[t][c];
            m = (v < m) ? v : m;
        }
        atomicMin(&keys[v0 + t], m);
    }
}

// ---------------------------------------------------------------------------
__global__ __launch_bounds__(256)
void vq_gather_kernel(const unsigned long long* __restrict__ keys,
                      const float* __restrict__ cb,
                      float* __restrict__ zq, float* __restrict__ idx_out)
{
    __shared__ int sidx[64];
    const int t = threadIdx.x;
    const int v0 = blockIdx.x * 64;
    if (t < 64) {
        int idx = (int)(keys[v0 + t] & 0xFFFFFFFFull);
        sidx[t] = idx;
        idx_out[v0 + t] = (float)idx;
    }
    __syncthreads();
    const int vl = t & 63;
    const int cg = t >> 6;
    const int v = v0 + vl;
    const int n = v >> 10;
    const int hw = v & 1023;
    const float* crow = cb + (size_t)sidx[vl] * 512;
    float* zqN = zq + (size_t)n * 512 * 1024;
    for (int c0 = cg * 4; c0 < 512; c0 += 16) {
        float4 vv = *(const float4*)(crow + c0);
        zqN[(size_t)(c0 + 0) * 1024 + hw] = vv.x;
        zqN[(size_t)(c0 + 1) * 1024 + hw] = vv.y;
        zqN[(size_t)(c0 + 2) * 1024 + hw] = vv.z;
        zqN[(size_t)(c0 + 3) * 1024 + hw] = vv.w;
    }
}

// ---------------------------------------------------------------------------
// ConvTranspose2d k=3 s=2 p=1 op=1 + ReLU, bf16 output.
// ---------------------------------------------------------------------------
template<int TIC, typename TIN>
__global__ __launch_bounds__(256)
void deconv_kernel(const TIN* __restrict__ in,   // [N,CIN,IH,IW]
                   const float* __restrict__ w,  // torch [CIN,COUT,3,3]
                   const float* __restrict__ bias,
                   unsigned short* __restrict__ out, // bf16 [N,COUT,2IH,2IW]
                   int CIN, int COUT, int IH, int IW)
{
    constexpr int TPY = 4, TPX = 16;
    __shared__ float s_in[TIC][TPY + 1][TPX + 1];
    __shared__ float s_w[64][TIC * 9 + 1];

    const int tid = threadIdx.x;
    const int tx = tid & 15;
    const int ty = tid >> 4;

    const int ntx = IW / TPX;
    const int tileX = blockIdx.x % ntx;
    const int tileY = blockIdx.x / ntx;
    const int x0 = tileX * TPX;
    const int y0 = tileY * TPY;
    const int co0 = blockIdx.y * 64;
    const int n = blockIdx.z;

    const TIN* inN = in + (size_t)n * CIN * IH * IW;
    const int OH = IH * 2, OW = IW * 2;

    float acc[4][4][2][2] = {};

    for (int c0 = 0; c0 < CIN; c0 += TIC) {
        for (int e = tid; e < TIC * (TPY + 1) * (TPX + 1); e += 256) {
            int ci = e / ((TPY + 1) * (TPX + 1));
            int r  = e % ((TPY + 1) * (TPX + 1));
            int yy = r / (TPX + 1), xx = r % (TPX + 1);
            int gy = y0 + yy, gx = x0 + xx;
            float v = 0.f;
            if (gy < IH && gx < IW)
                v = ldv(&inN[(size_t)(c0 + ci) * IH * IW + (size_t)gy * IW + gx]);
            s_in[ci][yy][xx] = v;
        }
        for (int e = tid; e < 64 * TIC * 9; e += 256) {
            int ci = e / (64 * 9);
            int r  = e % (64 * 9);
            s_w[r / 9][ci * 9 + (r % 9)] =
                w[((size_t)(c0 + ci) * COUT + co0) * 9 + r];
        }
        __syncthreads();
#pragma unroll
        for (int ci = 0; ci < TIC; ++ci) {
            float iv[TPY + 1][2];
#pragma unroll
            for (int yy = 0; yy < TPY + 1; yy++) {
                iv[yy][0] = s_in[ci][yy][tx];
                iv[yy][1] = s_in[ci][yy][tx + 1];
            }
#pragma unroll
            for (int i = 0; i < 4; i++) {
                float w9[9];
#pragma unroll
                for (int k = 0; k < 9; k++) w9[k] = s_w[ty * 4 + i][ci * 9 + k];
#pragma unroll
                for (int j = 0; j < 4; j++) {
                    acc[i][j][0][0] += w9[4] * iv[j][0];
                    acc[i][j][0][1] += w9[3] * iv[j][1];
                    acc[i][j][0][1] += w9[5] * iv[j][0];
                    acc[i][j][1][0] += w9[1] * iv[j + 1][0];
                    acc[i][j][1][0] += w9[7] * iv[j][0];
                    acc[i][j][1][1] += w9[0] * iv[j + 1][1];
                    acc[i][j][1][1] += w9[2] * iv[j + 1][0];
                    acc[i][j][1][1] += w9[6] * iv[j][1];
                    acc[i][j][1][1] += w9[8] * iv[j][0];
                }
            }
        }
        __syncthreads();
    }

#pragma unroll
    for (int i = 0; i < 4; i++) {
        const int co = co0 + ty * 4 + i;
        const float b = bias[co];
        unsigned short* outC = out + (size_t)(n * COUT + co) * OH * OW;
#pragma unroll
        for (int j = 0; j < 4; j++) {
#pragma unroll
            for (int ry = 0; ry < 2; ry++) {
                const int oy = 2 * (y0 + j) + ry;
                unsigned short* p = outC + (size_t)oy * OW + 2 * (x0 + tx);
                p[0] = f2bf(fmaxf(acc[i][j][ry][0] + b, 0.f));
                p[1] = f2bf(fmaxf(acc[i][j][ry][1] + b, 0.f));
            }
        }
    }
}

// ---------------------------------------------------------------------------
// Final conv 64->3 + sigmoid. bf16 input, fp32 output into d_out.
// ---------------------------------------------------------------------------
__global__ __launch_bounds__(256)
void conv_out_kernel(const unsigned short* __restrict__ in, // [16,64,256,256] bf16
                     const float* __restrict__ w,           // [3,64,3,3]
                     const float* __restrict__ bias,
                     float* __restrict__ out)               // [16,3,256,256]
{
    constexpr int TIC = 4;
    __shared__ float s_in[TIC][3][258];
    const int t = threadIdx.x;
    const int y = blockIdx.x;
    const int n = blockIdx.y;
    const unsigned short* inN = in + (size_t)n * 64 * 65536;
    float acc0 = bias[0], acc1 = bias[1], acc2 = bias[2];

    for (int c0 = 0; c0 < 64; c0 += TIC) {
        for (int e = t; e < TIC * 3 * 258; e += 256) {
            int ci = e / 774;
            int r  = e % 774;
            int ry = r / 258, xx = r % 258;
            int gy = y - 1 + ry, gx = xx - 1;
            float v = 0.f;
            if ((unsigned)gy < 256u && (unsigned)gx < 256u)
                v = bf2f(inN[(size_t)(c0 + ci) * 65536 + gy * 256 + gx]);
            s_in[ci][ry][xx] = v;
        }
        __syncthreads();
#pragma unroll
        for (int ci = 0; ci < TIC; ++ci) {
            float iv[3][3];
#pragma unroll
            for (int ry = 0; ry < 3; ry++)
#pragma unroll
                for (int kx = 0; kx < 3; kx++)
                    iv[ry][kx] = s_in[ci][ry][t + kx];
#pragma unroll
            for (int k = 0; k < 9; k++) {
                const float v = iv[k / 3][k % 3];
                acc0 += w[(0 * 64 + c0 + ci) * 9 + k] * v;
                acc1 += w[(1 * 64 + c0 + ci) * 9 + k] * v;
                acc2 += w[(2 * 64 + c0 + ci) * 9 + k] * v;
            }
        }
        __syncthreads();
    }
    const size_t o = (size_t)((n * 3 + 0) * 256 + y) * 256 + t;
    out[o]          = 1.f / (1.f + __expf(-acc0));
    out[o + 65536]  = 1.f / (1.f + __expf(-acc1));
    out[o + 131072] = 1.f / (1.f + __expf(-acc2));
}

// ---------------------------------------------------------------------------
// Workspace (peak 201.5 MB):
//   R0 @0        (134.2M): h2 f32  ->  Z f32 @+0 | ZQ f32 @+33.5M | g1 bf16 @+67.1M
//                          -> g3 bf16 @+0 (full 134.2M)
//   R1 @134.2M   ( 67.1M): h3 f32  ->  g2 bf16 (full)
//   keys @201.3M (128K), cn (+32K)
// ---------------------------------------------------------------------------
extern "C" void kernel_launch(void* const* d_in, const int* in_sizes, int n_in,
                              void* d_out, int out_size, void* d_ws, size_t ws_size,
                              hipStream_t stream)
{
    const float* x   = (const float*)d_in[0];
    const float* w1  = (const float*)d_in[1];
    const float* b1  = (const float*)d_in[2];
    const float* w2  = (const float*)d_in[3];
    const float* b2  = (const float*)d_in[4];
    const float* w3  = (const float*)d_in[5];
    const float* b3  = (const float*)d_in[6];
    const float* w4  = (const float*)d_in[7];
    const float* b4  = (const float*)d_in[8];
    const float* cb  = (const float*)d_in[9];
    const float* d1w = (const float*)d_in[10];
    const float* d1b = (const float*)d_in[11];
    const float* d2w = (const float*)d_in[12];
    const float* d2b = (const float*)d_in[13];
    const float* d3w = (const float*)d_in[14];
    const float* d3b = (const float*)d_in[15];
    const float* wo  = (const float*)d_in[16];
    const float* bo  = (const float*)d_in[17];

    char* ws = (char*)d_ws;
    float* H2 = (float*)(ws);                                  // [16,128,128,128] f32
    float* H3 = (float*)(ws + 134217728);                      // [16,256,64,64]  f32
    float* Z  = (float*)(ws);                                  // [16,512,32,32]  f32
    float* ZQ = (float*)(ws + 33554432);                       // [16,512,32,32]  f32
    unsigned short* G1 = (unsigned short*)(ws + 67108864);     // [16,256,64,64]  bf16
    unsigned short* G2 = (unsigned short*)(ws + 134217728);    // [16,128,128,128] bf16
    unsigned short* G3 = (unsigned short*)(ws);                // [16,64,256,256] bf16
    unsigned long long* keys = (unsigned long long*)(ws + 201326592);
    float* cn = (float*)(ws + 201326592 + 131072);

    float* xrec = (float*)d_out;
    float* idxf = (float*)d_out + (size_t)16 * 3 * 256 * 256;

    // ---- encoder (all fp32 — preserves VQ argmin fidelity) ----
    fused_conv12_kernel<<<dim3(128, 2, 16), 256, 0, stream>>>(x, w1, b1, w2, b2, H2);
    conv3x3s2_kernel<4, true ><<<dim3(32, 4, 16), 256, 0, stream>>>(H2, w3, b3, H3, 128, 256, 128, 128, 64, 64);
    conv3x3s2_kernel<4, false><<<dim3(8,  8, 16), 256, 0, stream>>>(H3, w4, b4, Z,  256, 512, 64,  64,  32, 32);

    // ---- vector quantization (fp32 exact) ----
    cnorm_kernel<<<8192, 64, 0, stream>>>(cb, cn);
    init_keys_kernel<<<64, 256, 0, stream>>>(keys);
    vq_dist_kernel<<<dim3(128, 64), 256, 0, stream>>>(Z, cb, cn, keys);
    vq_gather_kernel<<<256, 256, 0, stream>>>(keys, cb, ZQ, idxf);

    // ---- decoder (bf16 activations) ----
    deconv_kernel<4, float         ><<<dim3(16,  4, 16), 256, 0, stream>>>(ZQ, d1w, d1b, G1, 512, 256, 32,  32);
    deconv_kernel<4, unsigned short><<<dim3(64,  2, 16), 256, 0, stream>>>(G1, d2w, d2b, G2, 256, 128, 64,  64);
    deconv_kernel<4, unsigned short><<<dim3(256, 1, 16), 256, 0, stream>>>(G2, d3w, d3b, G3, 128, 64,  128, 128);
    conv_out_kernel<<<dim3(256, 16), 256, 0, stream>>>(G3, wo, bo, xrec);
}